// Round 1
// baseline (951.956 us; speedup 1.0000x reference)
//
#include <hip/hip_runtime.h>
#include <hip/hip_bf16.h>

// LocalizedFiltering: two shifted 2-tap causal convs (as GEMMs) + residual + RMSNorm.
// E=1024, BS=8, L=8192, N=65536. Extended rows per seq: 8193 (row 0 = cache row).

#define EDIM 1024
#define HDIM 512
#define LSEQ 8192
#define BSEQ 8
#define SEQR 8193                 // L+1
#define MTOT (BSEQ * SEQR)        // 65544 extended rows
#define MPAD 65664                // 513 * 128
#define PAIR_ROWS (2 * SEQR)      // 16386
#define PAIR_PAD 16512            // 129 * 128
#define N1 1024
#define N2 2048

using v8s = __attribute__((ext_vector_type(8))) short;
using v4f = __attribute__((ext_vector_type(4))) float;

__device__ __forceinline__ unsigned short f2b(float f) {
  union { float f; unsigned u; } v; v.f = f;
  unsigned r = v.u + 0x7fffu + ((v.u >> 16) & 1u);   // RNE
  return (unsigned short)(r >> 16);
}
__device__ __forceinline__ float b2f(unsigned short h) {
  union { unsigned u; float f; } v; v.u = ((unsigned)h) << 16; return v.f;
}
__device__ __forceinline__ void gl_lds16(const void* g, void* l) {
  __builtin_amdgcn_global_load_lds((const __attribute__((address_space(1))) void*)g,
                                   (__attribute__((address_space(3))) void*)l, 16, 0, 0);
}

// ---------------- prep: transpose + convert weights to bf16 [C][R] ----------------
__global__ __launch_bounds__(256) void transpose_cvt(const float* __restrict__ src,
                                                     unsigned short* __restrict__ dst,
                                                     int R, int C) {
  __shared__ float t[64][65];
  const int c0 = blockIdx.x * 64, r0 = blockIdx.y * 64;
  const int tx = threadIdx.x & 63, ty = threadIdx.x >> 6;  // ty in [0,4)
#pragma unroll
  for (int yy = 0; yy < 64; yy += 4)
    t[yy + ty][tx] = src[(size_t)(r0 + yy + ty) * C + c0 + tx];
  __syncthreads();
#pragma unroll
  for (int yy = 0; yy < 64; yy += 4)
    dst[(size_t)(c0 + yy + ty) * R + r0 + tx] = f2b(t[tx][yy + ty]);
}

// gather the 8 lf2 cache rows as bf16
__global__ void prep_small(const float* __restrict__ lf2, const int* __restrict__ preidx,
                           unsigned short* __restrict__ c2b) {
  const int tid = threadIdx.x;  // 512
#pragma unroll
  for (int b = 0; b < BSEQ; ++b)
    c2b[b * HDIM + tid] = f2b(lf2[(size_t)preidx[b] * HDIM + tid]);
}

// ---------------- GEMM1: Z1[r] = Xe[r] @ W1  (M=MPAD, K=1024, N=1024) ----------------
__global__ __launch_bounds__(256) void gemm1_kernel(
    const float* __restrict__ inputs, const float* __restrict__ lf1,
    const int* __restrict__ preidx, const unsigned short* __restrict__ W1T,
    unsigned short* __restrict__ Z1) {
  __shared__ __align__(16) unsigned short sA[128 * 64];
  __shared__ __align__(16) unsigned short sB[128 * 64];
  const int tid = threadIdx.x;
  const int n0 = blockIdx.x * 128;   // n-tile fast -> A panel shared in L2/L3
  const int m0 = blockIdx.y * 128;
  const int w = tid >> 6, lane = tid & 63;
  const int wm = w >> 1, wn = w & 1;
  const int lr = lane & 15, lk = lane >> 4;
  const int srow = tid >> 3;         // 0..31
  const int sk8 = (tid & 7) * 8;     // k offset (elems)

  v4f acc[4][4];
#pragma unroll
  for (int i = 0; i < 4; ++i)
#pragma unroll
    for (int j = 0; j < 4; ++j) acc[i][j] = (v4f){0.f, 0.f, 0.f, 0.f};

  // source row pointer per staging issue (uniform per thread across K loop)
  const float* asrc[4];
#pragma unroll
  for (int ii = 0; ii < 4; ++ii) {
    const int r = m0 + ii * 32 + srow;
    if (r >= MTOT) {
      asrc[ii] = nullptr;  // pad rows -> zeros
    } else {
      const int b = r / SEQR, rr = r % SEQR;
      asrc[ii] = (rr == 0) ? (lf1 + (size_t)preidx[b] * EDIM)
                           : (inputs + (size_t)(b * LSEQ + rr - 1) * EDIM);
    }
  }

  for (int kt = 0; kt < EDIM; kt += 64) {
    // B tile: global_load_lds direct (W1T is [N1][K] bf16)
#pragma unroll
    for (int ii = 0; ii < 4; ++ii)
      gl_lds16(W1T + (size_t)(n0 + ii * 32 + srow) * EDIM + kt + sk8,
               &sB[(ii * 32 + srow) * 64 + sk8]);
    // A tile: reg-staged f32 -> bf16
#pragma unroll
    for (int ii = 0; ii < 4; ++ii) {
      v8s pk;
      if (asrc[ii]) {
        const float4 p0 = *(const float4*)(asrc[ii] + kt + sk8);
        const float4 p1 = *(const float4*)(asrc[ii] + kt + sk8 + 4);
        pk[0] = (short)f2b(p0.x); pk[1] = (short)f2b(p0.y);
        pk[2] = (short)f2b(p0.z); pk[3] = (short)f2b(p0.w);
        pk[4] = (short)f2b(p1.x); pk[5] = (short)f2b(p1.y);
        pk[6] = (short)f2b(p1.z); pk[7] = (short)f2b(p1.w);
      } else {
        pk = (v8s){0, 0, 0, 0, 0, 0, 0, 0};
      }
      *(v8s*)&sA[(ii * 32 + srow) * 64 + sk8] = pk;
    }
    __syncthreads();
#pragma unroll
    for (int kk = 0; kk < 64; kk += 32) {
      v8s af[4], bfr[4];
#pragma unroll
      for (int mr = 0; mr < 4; ++mr)
        af[mr] = *(const v8s*)&sA[(wm * 64 + mr * 16 + lr) * 64 + kk + lk * 8];
#pragma unroll
      for (int nc = 0; nc < 4; ++nc)
        bfr[nc] = *(const v8s*)&sB[(wn * 64 + nc * 16 + lr) * 64 + kk + lk * 8];
#pragma unroll
      for (int mr = 0; mr < 4; ++mr)
#pragma unroll
        for (int nc = 0; nc < 4; ++nc)
          acc[mr][nc] = __builtin_amdgcn_mfma_f32_16x16x32_bf16(af[mr], bfr[nc],
                                                                acc[mr][nc], 0, 0, 0);
    }
    __syncthreads();
  }
#pragma unroll
  for (int mr = 0; mr < 4; ++mr)
#pragma unroll
    for (int nc = 0; nc < 4; ++nc)
#pragma unroll
      for (int g = 0; g < 4; ++g) {
        const int row = m0 + wm * 64 + mr * 16 + lk * 4 + g;
        const int col = n0 + wn * 64 + nc * 16 + lr;
        Z1[(size_t)row * N1 + col] = f2b(acc[mr][nc][g]);
      }
}

// ------- GEMM2: Z2[r] = A2[r] @ W2, A2[r] = (r%SEQR==0) ? lf2row : Z1[r-1].lo+Z1[r].hi+b1 -------
__global__ __launch_bounds__(256) void gemm2_kernel(
    const unsigned short* __restrict__ Z1, const float* __restrict__ b1,
    const unsigned short* __restrict__ c2b, const unsigned short* __restrict__ W2T,
    unsigned short* __restrict__ Z2, int pair_base) {
  __shared__ __align__(16) unsigned short sA[128 * 64];
  __shared__ __align__(16) unsigned short sB[128 * 64];
  const int tid = threadIdx.x;
  const int n0 = blockIdx.x * 128;
  const int m0 = blockIdx.y * 128;  // local row within pair chunk
  const int w = tid >> 6, lane = tid & 63;
  const int wm = w >> 1, wn = w & 1;
  const int lr = lane & 15, lk = lane >> 4;
  const int srow = tid >> 3;
  const int sk8 = (tid & 7) * 8;

  v4f acc[4][4];
#pragma unroll
  for (int i = 0; i < 4; ++i)
#pragma unroll
    for (int j = 0; j < 4; ++j) acc[i][j] = (v4f){0.f, 0.f, 0.f, 0.f};

  int arow[4]; int isc[4];
#pragma unroll
  for (int ii = 0; ii < 4; ++ii) {
    int rg = pair_base + m0 + ii * 32 + srow;
    int r = (rg < MTOT) ? rg : (MTOT - 1);   // clamp pad rows (values irrelevant)
    const int b = r / SEQR, rr = r % SEQR;
    isc[ii] = (rr == 0);
    arow[ii] = isc[ii] ? b : r;
  }

  for (int kt = 0; kt < HDIM; kt += 64) {
#pragma unroll
    for (int ii = 0; ii < 4; ++ii)
      gl_lds16(W2T + (size_t)(n0 + ii * 32 + srow) * HDIM + kt + sk8,
               &sB[(ii * 32 + srow) * 64 + sk8]);
#pragma unroll
    for (int ii = 0; ii < 4; ++ii) {
      v8s pk;
      if (isc[ii]) {
        pk = *(const v8s*)&c2b[arow[ii] * HDIM + kt + sk8];
      } else {
        const v8s lo = *(const v8s*)&Z1[(size_t)(arow[ii] - 1) * N1 + kt + sk8];
        const v8s hi = *(const v8s*)&Z1[(size_t)arow[ii] * N1 + HDIM + kt + sk8];
        const float4 q0 = *(const float4*)(b1 + kt + sk8);
        const float4 q1 = *(const float4*)(b1 + kt + sk8 + 4);
        pk[0] = (short)f2b(b2f((unsigned short)lo[0]) + b2f((unsigned short)hi[0]) + q0.x);
        pk[1] = (short)f2b(b2f((unsigned short)lo[1]) + b2f((unsigned short)hi[1]) + q0.y);
        pk[2] = (short)f2b(b2f((unsigned short)lo[2]) + b2f((unsigned short)hi[2]) + q0.z);
        pk[3] = (short)f2b(b2f((unsigned short)lo[3]) + b2f((unsigned short)hi[3]) + q0.w);
        pk[4] = (short)f2b(b2f((unsigned short)lo[4]) + b2f((unsigned short)hi[4]) + q1.x);
        pk[5] = (short)f2b(b2f((unsigned short)lo[5]) + b2f((unsigned short)hi[5]) + q1.y);
        pk[6] = (short)f2b(b2f((unsigned short)lo[6]) + b2f((unsigned short)hi[6]) + q1.z);
        pk[7] = (short)f2b(b2f((unsigned short)lo[7]) + b2f((unsigned short)hi[7]) + q1.w);
      }
      *(v8s*)&sA[(ii * 32 + srow) * 64 + sk8] = pk;
    }
    __syncthreads();
#pragma unroll
    for (int kk = 0; kk < 64; kk += 32) {
      v8s af[4], bfr[4];
#pragma unroll
      for (int mr = 0; mr < 4; ++mr)
        af[mr] = *(const v8s*)&sA[(wm * 64 + mr * 16 + lr) * 64 + kk + lk * 8];
#pragma unroll
      for (int nc = 0; nc < 4; ++nc)
        bfr[nc] = *(const v8s*)&sB[(wn * 64 + nc * 16 + lr) * 64 + kk + lk * 8];
#pragma unroll
      for (int mr = 0; mr < 4; ++mr)
#pragma unroll
        for (int nc = 0; nc < 4; ++nc)
          acc[mr][nc] = __builtin_amdgcn_mfma_f32_16x16x32_bf16(af[mr], bfr[nc],
                                                                acc[mr][nc], 0, 0, 0);
    }
    __syncthreads();
  }
#pragma unroll
  for (int mr = 0; mr < 4; ++mr)
#pragma unroll
    for (int nc = 0; nc < 4; ++nc)
#pragma unroll
      for (int g = 0; g < 4; ++g) {
        const int row = m0 + wm * 64 + mr * 16 + lk * 4 + g;  // local row
        const int col = n0 + wn * 64 + nc * 16 + lr;
        Z2[(size_t)row * N2 + col] = f2b(acc[mr][nc][g]);
      }
}

// ---------- epilogue: out2 combine + b2 + residual + RMSNorm, one block per token ----------
__global__ __launch_bounds__(256) void epilogue_kernel(
    const unsigned short* __restrict__ Z2, const float* __restrict__ inputs,
    const float* __restrict__ b2, const float* __restrict__ lnw,
    float* __restrict__ out, int pair) {
  const int tl = blockIdx.x;             // 0..16383 within pair
  const int sb = tl >> 13, t = tl & (LSEQ - 1);
  const int b = pair * 2 + sb;
  const size_t rl = (size_t)sb * SEQR + t;    // local Z2 row
  const size_t tok = (size_t)b * LSEQ + t;
  const int tid = threadIdx.x;
  const int j0 = tid * 4;

  const ushort4 zl = *(const ushort4*)&Z2[rl * N2 + j0];
  const ushort4 zh = *(const ushort4*)&Z2[(rl + 1) * N2 + EDIM + j0];
  const float4 inp = *(const float4*)&inputs[tok * EDIM + j0];
  const float4 bb = *(const float4*)&b2[j0];
  const float4 lw = *(const float4*)&lnw[j0];

  const float x0 = b2f(zl.x) + b2f(zh.x) + bb.x + inp.x;
  const float x1 = b2f(zl.y) + b2f(zh.y) + bb.y + inp.y;
  const float x2 = b2f(zl.z) + b2f(zh.z) + bb.z + inp.z;
  const float x3 = b2f(zl.w) + b2f(zh.w) + bb.w + inp.w;

  float ss = x0 * x0 + x1 * x1 + x2 * x2 + x3 * x3;
#pragma unroll
  for (int o = 32; o > 0; o >>= 1) ss += __shfl_xor(ss, o, 64);
  __shared__ float sp[4];
  if ((tid & 63) == 0) sp[tid >> 6] = ss;
  __syncthreads();
  const float tot = sp[0] + sp[1] + sp[2] + sp[3];
  const float scale = rsqrtf(tot * (1.0f / EDIM) + 1e-6f);

  float4 o4;
  o4.x = x0 * scale * lw.x; o4.y = x1 * scale * lw.y;
  o4.z = x2 * scale * lw.z; o4.w = x3 * scale * lw.w;
  *(float4*)&out[tok * EDIM + j0] = o4;
}

// -------------------------------- launch --------------------------------
extern "C" void kernel_launch(void* const* d_in, const int* in_sizes, int n_in,
                              void* d_out, int out_size, void* d_ws, size_t ws_size,
                              hipStream_t stream) {
  const float* inputs = (const float*)d_in[0];
  const float* W1 = (const float*)d_in[1];
  const float* W2 = (const float*)d_in[2];
  const float* b1 = (const float*)d_in[3];
  const float* b2 = (const float*)d_in[4];
  const float* lnw = (const float*)d_in[5];
  const float* lf1 = (const float*)d_in[6];
  const float* lf2 = (const float*)d_in[7];
  const int* preidx = (const int*)d_in[8];
  float* out = (float*)d_out;

  char* ws = (char*)d_ws;
  unsigned short* Z1  = (unsigned short*)(ws);               // MPAD x 1024 bf16 = 134,479,872 B
  unsigned short* W1T = (unsigned short*)(ws + 134479872);   // 1024 x 1024 bf16
  unsigned short* W2T = (unsigned short*)(ws + 136577024);   // 2048 x 512 bf16
  unsigned short* c2b = (unsigned short*)(ws + 138674176);   // 8 x 512 bf16
  unsigned short* Z2  = (unsigned short*)(ws + 138682368);   // PAIR_PAD x 2048 bf16 = 67,633,152 B
  // total ws use: 206,315,520 B

  transpose_cvt<<<dim3(16, 16), 256, 0, stream>>>(W1, W1T, 1024, 1024);
  transpose_cvt<<<dim3(32, 8), 256, 0, stream>>>(W2, W2T, 512, 2048);
  prep_small<<<1, 512, 0, stream>>>(lf2, preidx, c2b);

  gemm1_kernel<<<dim3(8, 513), 256, 0, stream>>>(inputs, lf1, preidx, W1T, Z1);

  for (int p = 0; p < 4; ++p) {
    gemm2_kernel<<<dim3(16, 129), 256, 0, stream>>>(Z1, b1, c2b, W2T, Z2, p * PAIR_ROWS);
    epilogue_kernel<<<16384, 256, 0, stream>>>(Z2, inputs, b2, lnw, out, p);
  }
}

// Round 2
// 630.891 us; speedup vs baseline: 1.5089x; 1.5089x over previous
//
#include <hip/hip_runtime.h>
#include <hip/hip_bf16.h>

// LocalizedFiltering: two shifted 2-tap causal convs (as bf16 GEMMs) + residual + RMSNorm.
// E=1024, BS=8, L=8192. Extended rows per seq: 8193 (row 0 = cache row).
// Pipeline per pair-chunk (2 seqs): cvt(Xbf) -> gemm(Z1) -> a2_prep -> gemm(Z2) -> epilogue.

#define EDIM 1024
#define HDIM 512
#define LSEQ 8192
#define BSEQ 8
#define SEQR 8193                 // L+1
#define MTOT (BSEQ * SEQR)        // 65544 extended rows
#define PAIR_ROWS (2 * SEQR)      // 16386
#define PAIR_PAD 16512            // 129 * 128
#define N1 1024
#define N2 2048

using v8s = __attribute__((ext_vector_type(8))) short;
using v4f = __attribute__((ext_vector_type(4))) float;

__device__ __forceinline__ unsigned short f2b(float f) {
  union { float f; unsigned u; } v; v.f = f;
  unsigned r = v.u + 0x7fffu + ((v.u >> 16) & 1u);   // RNE
  return (unsigned short)(r >> 16);
}
__device__ __forceinline__ float b2f(unsigned short h) {
  union { unsigned u; float f; } v; v.u = ((unsigned)h) << 16; return v.f;
}
__device__ __forceinline__ void gl_lds16(const void* g, void* l) {
  __builtin_amdgcn_global_load_lds((const __attribute__((address_space(1))) void*)g,
                                   (__attribute__((address_space(3))) void*)l, 16, 0, 0);
}

// ---------------- prep: transpose + convert weights to bf16 [C][R] ----------------
__global__ __launch_bounds__(256) void transpose_cvt(const float* __restrict__ src,
                                                     unsigned short* __restrict__ dst,
                                                     int R, int C) {
  __shared__ float t[64][65];
  const int c0 = blockIdx.x * 64, r0 = blockIdx.y * 64;
  const int tx = threadIdx.x & 63, ty = threadIdx.x >> 6;  // ty in [0,4)
#pragma unroll
  for (int yy = 0; yy < 64; yy += 4)
    t[yy + ty][tx] = src[(size_t)(r0 + yy + ty) * C + c0 + tx];
  __syncthreads();
#pragma unroll
  for (int yy = 0; yy < 64; yy += 4)
    dst[(size_t)(c0 + yy + ty) * R + r0 + tx] = f2b(t[tx][yy + ty]);
}

// gather the 8 lf2 cache rows as bf16
__global__ void prep_small(const float* __restrict__ lf2, const int* __restrict__ preidx,
                           unsigned short* __restrict__ c2b) {
  const int tid = threadIdx.x;  // 512
#pragma unroll
  for (int b = 0; b < BSEQ; ++b)
    c2b[b * HDIM + tid] = f2b(lf2[(size_t)preidx[b] * HDIM + tid]);
}

// ---------------- cvt: build bf16 extended-A chunk (cache row + tokens, zero pad) ----------------
__global__ __launch_bounds__(256) void cvt_chunk(const float* __restrict__ inputs,
                                                 const float* __restrict__ lf1,
                                                 const int* __restrict__ preidx,
                                                 unsigned short* __restrict__ Xbf, int pair) {
  const int rl = blockIdx.x * 4 + (threadIdx.x >> 6);   // local ext row, 0..16511
  const int lane = threadIdx.x & 63;
  unsigned short* dst = Xbf + (size_t)rl * EDIM;
  if (rl >= PAIR_ROWS) {                                // pad rows -> zeros
#pragma unroll
    for (int c = lane * 4; c < EDIM; c += 256)
      *(ushort4*)&dst[c] = (ushort4){0, 0, 0, 0};
    return;
  }
  const int half = (rl >= SEQR);
  const int rr = rl - half * SEQR;
  const int b = pair * 2 + half;
  const float* src = (rr == 0) ? (lf1 + (size_t)preidx[b] * EDIM)
                               : (inputs + (size_t)(b * LSEQ + rr - 1) * EDIM);
#pragma unroll
  for (int c = lane * 4; c < EDIM; c += 256) {
    const float4 v = *(const float4*)(src + c);
    *(ushort4*)&dst[c] = (ushort4){f2b(v.x), f2b(v.y), f2b(v.z), f2b(v.w)};
  }
}

// ---------------- A2 prebuild: A2[rl] = bf16(Z1[rl-1].lo + Z1[rl].hi + b1) ----------------
__global__ __launch_bounds__(256) void a2_prep(const unsigned short* __restrict__ Z1,
                                               const float* __restrict__ b1,
                                               const unsigned short* __restrict__ c2b,
                                               unsigned short* __restrict__ A2, int pair) {
  const int rl = blockIdx.x * 4 + (threadIdx.x >> 6);
  const int lane = threadIdx.x & 63;
  unsigned short* dst = A2 + (size_t)rl * HDIM;
  if (rl >= PAIR_ROWS) {
#pragma unroll
    for (int c = lane * 4; c < HDIM; c += 256)
      *(ushort4*)&dst[c] = (ushort4){0, 0, 0, 0};
    return;
  }
  const int half = (rl >= SEQR);
  const int rr = rl - half * SEQR;
  if (rr == 0) {
    const int b = pair * 2 + half;
#pragma unroll
    for (int c = lane * 4; c < HDIM; c += 256)
      *(ushort4*)&dst[c] = *(const ushort4*)&c2b[b * HDIM + c];
    return;
  }
#pragma unroll
  for (int c = lane * 4; c < HDIM; c += 256) {
    const ushort4 lo = *(const ushort4*)&Z1[(size_t)(rl - 1) * N1 + c];
    const ushort4 hi = *(const ushort4*)&Z1[(size_t)rl * N1 + HDIM + c];
    const float4 q = *(const float4*)(b1 + c);
    *(ushort4*)&dst[c] = (ushort4){f2b(b2f(lo.x) + b2f(hi.x) + q.x),
                                   f2b(b2f(lo.y) + b2f(hi.y) + q.y),
                                   f2b(b2f(lo.z) + b2f(hi.z) + q.z),
                                   f2b(b2f(lo.w) + b2f(hi.w) + q.w)};
  }
}

// ------- unified GEMM: C[M][N] = A[M][K] @ B[N][K]^T, all bf16, 128x128 tile, BK=64 -------
// grid 1-D nwg = (M/128)*(N/128); XCD swizzle t=(h&7)*cpx+(h>>3); T2 XOR slot swizzle.
__global__ __launch_bounds__(256) void gemm_tile(const unsigned short* __restrict__ A,
                                                 const unsigned short* __restrict__ B,
                                                 unsigned short* __restrict__ C,
                                                 int K, int N, int lognt, int cpx) {
  __shared__ __align__(16) unsigned short sA[128 * 64];
  __shared__ __align__(16) unsigned short sB[128 * 64];
  const int h = blockIdx.x;
  const int t = (h & 7) * cpx + (h >> 3);
  const int n0 = (t & ((1 << lognt) - 1)) * 128;
  const int m0 = (t >> lognt) * 128;
  const int tid = threadIdx.x;
  const int w = tid >> 6, lane = tid & 63;
  const int wm = w >> 1, wn = w & 1;
  const int lr = lane & 15, lk = lane >> 4;
  const int srow = tid >> 3;              // 0..31
  const int slot = (tid & 7) ^ (srow & 7);  // pre-swizzled global 16B-slot
  const int ra7 = lr & 7;

  v4f acc[4][4];
#pragma unroll
  for (int i = 0; i < 4; ++i)
#pragma unroll
    for (int j = 0; j < 4; ++j) acc[i][j] = (v4f){0.f, 0.f, 0.f, 0.f};

  const unsigned short* aBase = A + (size_t)(m0 + srow) * K + slot * 8;
  const unsigned short* bBase = B + (size_t)(n0 + srow) * K + slot * 8;
  unsigned short* sAw = &sA[srow * 64 + (tid & 7) * 8];   // linear LDS dest
  unsigned short* sBw = &sB[srow * 64 + (tid & 7) * 8];

  for (int kt = 0; kt < K; kt += 64) {
#pragma unroll
    for (int ii = 0; ii < 4; ++ii)
      gl_lds16(aBase + (size_t)ii * 32 * K + kt, sAw + ii * 32 * 64);
#pragma unroll
    for (int ii = 0; ii < 4; ++ii)
      gl_lds16(bBase + (size_t)ii * 32 * K + kt, sBw + ii * 32 * 64);
    __syncthreads();
#pragma unroll
    for (int kk = 0; kk < 64; kk += 32) {
      const int g = (kk >> 3) + lk;
      const int so = ((g ^ ra7) << 3);
      v8s af[4], bfr[4];
#pragma unroll
      for (int mr = 0; mr < 4; ++mr)
        af[mr] = *(const v8s*)&sA[(wm * 64 + mr * 16 + lr) * 64 + so];
#pragma unroll
      for (int nc = 0; nc < 4; ++nc)
        bfr[nc] = *(const v8s*)&sB[(wn * 64 + nc * 16 + lr) * 64 + so];
#pragma unroll
      for (int mr = 0; mr < 4; ++mr)
#pragma unroll
        for (int nc = 0; nc < 4; ++nc)
          acc[mr][nc] = __builtin_amdgcn_mfma_f32_16x16x32_bf16(af[mr], bfr[nc],
                                                                acc[mr][nc], 0, 0, 0);
    }
    __syncthreads();
  }
#pragma unroll
  for (int mr = 0; mr < 4; ++mr)
#pragma unroll
    for (int nc = 0; nc < 4; ++nc)
#pragma unroll
      for (int g = 0; g < 4; ++g) {
        const int row = m0 + wm * 64 + mr * 16 + lk * 4 + g;
        const int col = n0 + wn * 64 + nc * 16 + lr;
        C[(size_t)row * N + col] = f2b(acc[mr][nc][g]);
      }
}

// ---------- epilogue: out2 combine + b2 + residual + RMSNorm, one block per token ----------
__global__ __launch_bounds__(256) void epilogue_kernel(
    const unsigned short* __restrict__ Z2, const float* __restrict__ inputs,
    const float* __restrict__ b2, const float* __restrict__ lnw,
    float* __restrict__ out, int pair) {
  const int tl = blockIdx.x;             // 0..16383 within pair
  const int sb = tl >> 13, t = tl & (LSEQ - 1);
  const int b = pair * 2 + sb;
  const size_t rl = (size_t)sb * SEQR + t;    // local Z2 row (prev ext row)
  const size_t tok = (size_t)b * LSEQ + t;
  const int tid = threadIdx.x;
  const int j0 = tid * 4;

  const ushort4 zl = *(const ushort4*)&Z2[rl * N2 + j0];
  const ushort4 zh = *(const ushort4*)&Z2[(rl + 1) * N2 + EDIM + j0];
  const float4 inp = *(const float4*)&inputs[tok * EDIM + j0];
  const float4 bb = *(const float4*)&b2[j0];
  const float4 lw = *(const float4*)&lnw[j0];

  const float x0 = b2f(zl.x) + b2f(zh.x) + bb.x + inp.x;
  const float x1 = b2f(zl.y) + b2f(zh.y) + bb.y + inp.y;
  const float x2 = b2f(zl.z) + b2f(zh.z) + bb.z + inp.z;
  const float x3 = b2f(zl.w) + b2f(zh.w) + bb.w + inp.w;

  float ss = x0 * x0 + x1 * x1 + x2 * x2 + x3 * x3;
#pragma unroll
  for (int o = 32; o > 0; o >>= 1) ss += __shfl_xor(ss, o, 64);
  __shared__ float sp[4];
  if ((tid & 63) == 0) sp[tid >> 6] = ss;
  __syncthreads();
  const float tot = sp[0] + sp[1] + sp[2] + sp[3];
  const float scale = rsqrtf(tot * (1.0f / EDIM) + 1e-6f);

  float4 o4;
  o4.x = x0 * scale * lw.x; o4.y = x1 * scale * lw.y;
  o4.z = x2 * scale * lw.z; o4.w = x3 * scale * lw.w;
  *(float4*)&out[tok * EDIM + j0] = o4;
}

// -------------------------------- launch --------------------------------
extern "C" void kernel_launch(void* const* d_in, const int* in_sizes, int n_in,
                              void* d_out, int out_size, void* d_ws, size_t ws_size,
                              hipStream_t stream) {
  const float* inputs = (const float*)d_in[0];
  const float* W1 = (const float*)d_in[1];
  const float* W2 = (const float*)d_in[2];
  const float* b1 = (const float*)d_in[3];
  const float* b2 = (const float*)d_in[4];
  const float* lnw = (const float*)d_in[5];
  const float* lf1 = (const float*)d_in[6];
  const float* lf2 = (const float*)d_in[7];
  const int* preidx = (const int*)d_in[8];
  float* out = (float*)d_out;

  char* ws = (char*)d_ws;
  unsigned short* Xbf = (unsigned short*)(ws);               // 16512 x 1024 bf16 = 33,816,576 B
  unsigned short* Z1c = (unsigned short*)(ws + 33816576);    // 16512 x 1024 bf16 = 33,816,576 B
  unsigned short* A2c = (unsigned short*)(ws + 67633152);    // 16512 x  512 bf16 = 16,908,288 B
  unsigned short* Z2c = (unsigned short*)(ws + 84541440);    // 16512 x 2048 bf16 = 67,633,152 B
  unsigned short* W1T = (unsigned short*)(ws + 152174592);   // 1024 x 1024 bf16
  unsigned short* W2T = (unsigned short*)(ws + 154271744);   // 2048 x  512 bf16
  unsigned short* c2b = (unsigned short*)(ws + 156368896);   // 8 x 512 bf16
  // total ws use: 156,377,088 B (within round-1-proven 206 MB)

  transpose_cvt<<<dim3(16, 16), 256, 0, stream>>>(W1, W1T, 1024, 1024);
  transpose_cvt<<<dim3(32, 8), 256, 0, stream>>>(W2, W2T, 512, 2048);
  prep_small<<<1, 512, 0, stream>>>(lf2, preidx, c2b);

  for (int p = 0; p < 4; ++p) {
    cvt_chunk<<<PAIR_PAD / 4, 256, 0, stream>>>(inputs, lf1, preidx, Xbf, p);
    // GEMM1: M=16512, K=1024, N=1024 -> nwg = 129*8 = 1032, cpx = 129, lognt = 3
    gemm_tile<<<1032, 256, 0, stream>>>(Xbf, W1T, Z1c, 1024, 1024, 3, 129);
    a2_prep<<<PAIR_PAD / 4, 256, 0, stream>>>(Z1c, b1, c2b, A2c, p);
    // GEMM2: M=16512, K=512, N=2048 -> nwg = 129*16 = 2064, cpx = 258, lognt = 4
    gemm_tile<<<2064, 256, 0, stream>>>(A2c, W2T, Z2c, 512, 2048, 4, 258);
    epilogue_kernel<<<16384, 256, 0, stream>>>(Z2c, inputs, b2, lnw, out, p);
  }
}

// Round 4
// 546.767 us; speedup vs baseline: 1.7411x; 1.1539x over previous
//
#include <hip/hip_runtime.h>
#include <hip/hip_bf16.h>

// LocalizedFiltering: two shifted 2-tap causal convs (as bf16 GEMMs) + residual + RMSNorm.
// Full-size pipeline (ws ~1GB): cvt -> gemm1(counted-vmcnt 4-phase) -> a2 -> gemm2 -> epilogue.

#define EDIM 1024
#define HDIM 512
#define LSEQ 8192
#define BSEQ 8
#define SEQR 8193                 // L+1
#define MTOT (BSEQ * SEQR)        // 65544 extended rows
#define MPAD 65792                // 257 * 256
#define N1 1024
#define N2 2048

using v8s = __attribute__((ext_vector_type(8))) short;
using v4f = __attribute__((ext_vector_type(4))) float;

__device__ __forceinline__ unsigned short f2b(float f) {
  union { float f; unsigned u; } v; v.f = f;
  unsigned r = v.u + 0x7fffu + ((v.u >> 16) & 1u);   // RNE
  return (unsigned short)(r >> 16);
}
__device__ __forceinline__ float b2f(unsigned short h) {
  union { unsigned u; float f; } v; v.u = ((unsigned)h) << 16; return v.f;
}
__device__ __forceinline__ void gl_lds16(const void* g, void* l) {
  __builtin_amdgcn_global_load_lds((const __attribute__((address_space(1))) void*)g,
                                   (__attribute__((address_space(3))) void*)l, 16, 0, 0);
}

// ---------------- prep: transpose + convert weights to bf16 [C][R] ----------------
__global__ __launch_bounds__(256) void transpose_cvt(const float* __restrict__ src,
                                                     unsigned short* __restrict__ dst,
                                                     int R, int C) {
  __shared__ float t[64][65];
  const int c0 = blockIdx.x * 64, r0 = blockIdx.y * 64;
  const int tx = threadIdx.x & 63, ty = threadIdx.x >> 6;
#pragma unroll
  for (int yy = 0; yy < 64; yy += 4)
    t[yy + ty][tx] = src[(size_t)(r0 + yy + ty) * C + c0 + tx];
  __syncthreads();
#pragma unroll
  for (int yy = 0; yy < 64; yy += 4)
    dst[(size_t)(c0 + yy + ty) * R + r0 + tx] = f2b(t[tx][yy + ty]);
}

// gather the 8 lf2 cache rows as bf16
__global__ void prep_small(const float* __restrict__ lf2, const int* __restrict__ preidx,
                           unsigned short* __restrict__ c2b) {
  const int tid = threadIdx.x;  // 512
#pragma unroll
  for (int b = 0; b < BSEQ; ++b)
    c2b[b * HDIM + tid] = f2b(lf2[(size_t)preidx[b] * HDIM + tid]);
}

// ---------------- cvt: full bf16 extended-A (cache row + shifted tokens, zero pad) ----------------
__global__ __launch_bounds__(256) void cvt_full(const float* __restrict__ inputs,
                                                const float* __restrict__ lf1,
                                                const int* __restrict__ preidx,
                                                unsigned short* __restrict__ Xbf) {
  const int r = blockIdx.x * 4 + (threadIdx.x >> 6);   // global ext row, 0..65791
  const int lane = threadIdx.x & 63;
  unsigned short* dst = Xbf + (size_t)r * EDIM;
  if (r >= MTOT) {
#pragma unroll
    for (int c = lane * 4; c < EDIM; c += 256)
      *(ushort4*)&dst[c] = (ushort4){0, 0, 0, 0};
    return;
  }
  const int b = r / SEQR, rr = r % SEQR;
  const float* src = (rr == 0) ? (lf1 + (size_t)preidx[b] * EDIM)
                               : (inputs + (size_t)(b * LSEQ + rr - 1) * EDIM);
#pragma unroll
  for (int c = lane * 4; c < EDIM; c += 256) {
    const float4 v = *(const float4*)(src + c);
    *(ushort4*)&dst[c] = (ushort4){f2b(v.x), f2b(v.y), f2b(v.z), f2b(v.w)};
  }
}

// ---------------- A2 prebuild: A2[r] = bf16(Z1[r-1].lo + Z1[r].hi + b1) ----------------
__global__ __launch_bounds__(256) void a2_full(const unsigned short* __restrict__ Z1,
                                               const float* __restrict__ b1,
                                               const unsigned short* __restrict__ c2b,
                                               unsigned short* __restrict__ A2) {
  const int r = blockIdx.x * 4 + (threadIdx.x >> 6);
  const int lane = threadIdx.x & 63;
  unsigned short* dst = A2 + (size_t)r * HDIM;
  if (r >= MTOT) {
#pragma unroll
    for (int c = lane * 4; c < HDIM; c += 256)
      *(ushort4*)&dst[c] = (ushort4){0, 0, 0, 0};
    return;
  }
  const int b = r / SEQR, rr = r % SEQR;
  if (rr == 0) {
#pragma unroll
    for (int c = lane * 4; c < HDIM; c += 256)
      *(ushort4*)&dst[c] = *(const ushort4*)&c2b[b * HDIM + c];
    return;
  }
#pragma unroll
  for (int c = lane * 4; c < HDIM; c += 256) {
    const ushort4 lo = *(const ushort4*)&Z1[(size_t)(r - 1) * N1 + c];
    const ushort4 hi = *(const ushort4*)&Z1[(size_t)r * N1 + HDIM + c];
    const float4 q = *(const float4*)(b1 + c);
    *(ushort4*)&dst[c] = (ushort4){f2b(b2f(lo.x) + b2f(hi.x) + q.x),
                                   f2b(b2f(lo.y) + b2f(hi.y) + q.y),
                                   f2b(b2f(lo.z) + b2f(hi.z) + q.z),
                                   f2b(b2f(lo.w) + b2f(hi.w) + q.w)};
  }
}

// ======= 256x256 GEMM, BK=64, 512 thr / 8 waves (2m x 4n), 4-phase counted-vmcnt =======
// C[M][N] = A[M][K] @ B[N][K]^T (bf16 in, bf16 out). Phase p consumes A-quarter p
// (interleaved m: row = mr*32 + wm*16 + lr). Staging of tile t+1 issued one half-tile
// per phase in order B0,B1,A0,A1 into the idle buffer. Steady-state waits: vmcnt(4)
// mid-tile (drains A1 of current), vmcnt(2) at boundary (drains B0,B1,A0 of next;
// A1 stays in flight). LAST K-tile is peeled: no staging outstanding except A1(last),
// so its mid wait must be vmcnt(0) (round-3 bug: vmcnt(4) was a no-op there -> race).
#define PHASE(p)                                                                      \
  {                                                                                   \
    v8s af[2][2];                                                                     \
    _Pragma("unroll") for (int m2 = 0; m2 < 2; ++m2)                                  \
    _Pragma("unroll") for (int kx = 0; kx < 2; ++kx)                                  \
      af[m2][kx] = *(const v8s*)&lds[bo + ((2 * (p) + m2) * 32 + wm * 16 + lr) * 64 + \
                                     (((kx * 4 + lk) ^ ra7) << 3)];                   \
    __builtin_amdgcn_s_setprio(1);                                                    \
    _Pragma("unroll") for (int m2 = 0; m2 < 2; ++m2)                                  \
    _Pragma("unroll") for (int nc = 0; nc < 4; ++nc)                                  \
    _Pragma("unroll") for (int kx = 0; kx < 2; ++kx)                                  \
      acc[2 * (p) + m2][nc] = __builtin_amdgcn_mfma_f32_16x16x32_bf16(                \
          af[m2][kx], bf[nc][kx], acc[2 * (p) + m2][nc], 0, 0, 0);                    \
    __builtin_amdgcn_s_setprio(0);                                                    \
  }

#define LOAD_BFR(bo_)                                                                 \
  _Pragma("unroll") for (int nc = 0; nc < 4; ++nc)                                    \
  _Pragma("unroll") for (int kx = 0; kx < 2; ++kx)                                    \
    bf[nc][kx] = *(const v8s*)&lds[(bo_) + 16384 + (nc * 64 + wn * 16 + lr) * 64 +    \
                                   (((kx * 4 + lk) ^ ra7) << 3)];

template <int K, int NT>
__global__ __launch_bounds__(512, 2) void gemm8p(const unsigned short* __restrict__ A,
                                                 const unsigned short* __restrict__ B,
                                                 unsigned short* __restrict__ C,
                                                 int q, int r) {
  __shared__ __align__(16) unsigned short lds[65536];  // 2 bufs x (A 16384 + B 16384)
  constexpr int NTILES = K / 64;
  constexpr int N = NT * 256;
  const int h = blockIdx.x;
  const int xcd = h & 7, idx = h >> 3;
  const int t = (xcd < r ? xcd * (q + 1) : r * (q + 1) + (xcd - r) * q) + idx;
  const int mt = t / NT, nt = t % NT;   // n-fast: neighbors share A m-panel
  const size_t m0 = (size_t)mt * 256, n0 = (size_t)nt * 256;
  const int tid = threadIdx.x;
  const int w = tid >> 6, lane = tid & 63;
  const int wm = w >> 2, wn = w & 3;
  const int lr = lane & 15, lk = lane >> 4;
  const int ra7 = lr & 7;
  const int srow = tid >> 3, slot = tid & 7;
  const int gslot = slot ^ (srow & 7);            // pre-swizzled global 16B-slot
  const unsigned short* aSrc = A + (m0 + srow) * K + gslot * 8;
  const unsigned short* bSrc = B + (n0 + srow) * K + gslot * 8;
  const int dA = srow * 64 + slot * 8;            // linear LDS dest = wavebase + lane*16B

  auto stageA = [&](int buf, int hh, int tt) {
    const unsigned short* s = aSrc + (size_t)hh * 128 * K + (size_t)tt * 64;
    unsigned short* d = &lds[buf * 32768 + hh * 8192 + dA];
    gl_lds16(s, d);
    gl_lds16(s + (size_t)64 * K, d + 4096);
  };
  auto stageB = [&](int buf, int hh, int tt) {
    const unsigned short* s = bSrc + (size_t)hh * 128 * K + (size_t)tt * 64;
    unsigned short* d = &lds[buf * 32768 + 16384 + hh * 8192 + dA];
    gl_lds16(s, d);
    gl_lds16(s + (size_t)64 * K, d + 4096);
  };

  v4f acc[8][4];
#pragma unroll
  for (int i = 0; i < 8; ++i)
#pragma unroll
    for (int j = 0; j < 4; ++j) acc[i][j] = (v4f){0.f, 0.f, 0.f, 0.f};

  // prologue: stage tile 0; leave A1(0) in flight (drained by tile 0's mid wait)
  stageB(0, 0, 0); stageB(0, 1, 0); stageA(0, 0, 0); stageA(0, 1, 0);
  asm volatile("s_waitcnt vmcnt(2)" ::: "memory");
  __builtin_amdgcn_s_barrier();

  // main loop over tiles 0..NTILES-2 (always stages tile t0+1)
#pragma unroll 2
  for (int t0 = 0; t0 < NTILES - 1; ++t0) {
    const int bo = (t0 & 1) * 32768;
    const int nb = (t0 + 1) & 1;
    v8s bf[4][2];
    // ---- phase 0 ----
    stageB(nb, 0, t0 + 1);
    LOAD_BFR(bo)
    PHASE(0)
    // ---- phase 1 ----
    stageB(nb, 1, t0 + 1);
    PHASE(1)
    // mid-tile: A-half1 of current tile must have landed (6 outstanding -> drain 2)
    asm volatile("s_waitcnt vmcnt(4)" ::: "memory");
    __builtin_amdgcn_s_barrier();
    // ---- phase 2 ----
    stageA(nb, 0, t0 + 1);
    PHASE(2)
    // ---- phase 3 ----
    stageA(nb, 1, t0 + 1);
    PHASE(3)
    // boundary: drain B0,B1,A0 of next tile; A1(next) stays in flight
    asm volatile("s_waitcnt vmcnt(2)" ::: "memory");
    __builtin_amdgcn_s_barrier();
  }

  // ---- peeled last tile: only A1(last) outstanding; mid wait must fully drain ----
  {
    const int bo = ((NTILES - 1) & 1) * 32768;
    v8s bf[4][2];
    LOAD_BFR(bo)
    PHASE(0)
    PHASE(1)
    asm volatile("s_waitcnt vmcnt(0)" ::: "memory");
    __builtin_amdgcn_s_barrier();
    PHASE(2)
    PHASE(3)
  }

#pragma unroll
  for (int mr = 0; mr < 8; ++mr)
#pragma unroll
    for (int nc = 0; nc < 4; ++nc)
#pragma unroll
      for (int g = 0; g < 4; ++g) {
        const size_t row = m0 + mr * 32 + wm * 16 + lk * 4 + g;
        const size_t col = n0 + nc * 64 + wn * 16 + lr;
        C[row * N + col] = f2b(acc[mr][nc][g]);
      }
}

// ---------- epilogue: combine + b2 + residual(bf16 Xbf) + RMSNorm, one block per token ----------
__global__ __launch_bounds__(256) void epilogue_full(
    const unsigned short* __restrict__ Z2, const unsigned short* __restrict__ Xbf,
    const float* __restrict__ b2, const float* __restrict__ lnw,
    float* __restrict__ out) {
  const int g = blockIdx.x;              // 0..65535 token id
  const int b = g >> 13, t = g & (LSEQ - 1);
  const size_t r = (size_t)b * SEQR + t; // prev ext row
  const int tid = threadIdx.x;
  const int j0 = tid * 4;

  const ushort4 zl = *(const ushort4*)&Z2[r * N2 + j0];
  const ushort4 zh = *(const ushort4*)&Z2[(r + 1) * N2 + EDIM + j0];
  const ushort4 xb = *(const ushort4*)&Xbf[(r + 1) * EDIM + j0];  // = bf16(inputs[b,t])
  const float4 bb = *(const float4*)&b2[j0];
  const float4 lw = *(const float4*)&lnw[j0];

  const float x0 = b2f(zl.x) + b2f(zh.x) + bb.x + b2f(xb.x);
  const float x1 = b2f(zl.y) + b2f(zh.y) + bb.y + b2f(xb.y);
  const float x2 = b2f(zl.z) + b2f(zh.z) + bb.z + b2f(xb.z);
  const float x3 = b2f(zl.w) + b2f(zh.w) + bb.w + b2f(xb.w);

  float ss = x0 * x0 + x1 * x1 + x2 * x2 + x3 * x3;
#pragma unroll
  for (int o = 32; o > 0; o >>= 1) ss += __shfl_xor(ss, o, 64);
  __shared__ float sp[4];
  if ((tid & 63) == 0) sp[tid >> 6] = ss;
  __syncthreads();
  const float tot = sp[0] + sp[1] + sp[2] + sp[3];
  const float scale = rsqrtf(tot * (1.0f / EDIM) + 1e-6f);

  float4 o4;
  o4.x = x0 * scale * lw.x; o4.y = x1 * scale * lw.y;
  o4.z = x2 * scale * lw.z; o4.w = x3 * scale * lw.w;
  *(float4*)&out[(size_t)(b * LSEQ + t) * EDIM + j0] = o4;
}

// -------------------------------- launch --------------------------------
extern "C" void kernel_launch(void* const* d_in, const int* in_sizes, int n_in,
                              void* d_out, int out_size, void* d_ws, size_t ws_size,
                              hipStream_t stream) {
  const float* inputs = (const float*)d_in[0];
  const float* W1 = (const float*)d_in[1];
  const float* W2 = (const float*)d_in[2];
  const float* b1 = (const float*)d_in[3];
  const float* b2 = (const float*)d_in[4];
  const float* lnw = (const float*)d_in[5];
  const float* lf1 = (const float*)d_in[6];
  const float* lf2 = (const float*)d_in[7];
  const int* preidx = (const int*)d_in[8];
  float* out = (float*)d_out;

  char* ws = (char*)d_ws;
  unsigned short* Xbf = (unsigned short*)(ws);                 // MPAD x 1024 = 134,742,016 B
  unsigned short* Z1  = (unsigned short*)(ws + 134742016ULL);  // MPAD x 1024 = 134,742,016 B
  unsigned short* A2  = (unsigned short*)(ws + 269484032ULL);  // MPAD x  512 =  67,371,008 B
  unsigned short* Z2  = (unsigned short*)(ws + 336855040ULL);  // MPAD x 2048 = 269,484,032 B
  unsigned short* W1T = (unsigned short*)(ws + 606339072ULL);  // 1024 x 1024
  unsigned short* W2T = (unsigned short*)(ws + 608436224ULL);  // 2048 x  512
  unsigned short* c2b = (unsigned short*)(ws + 610533376ULL);  // 8 x 512
  // total ws use: ~610.5 MB

  transpose_cvt<<<dim3(16, 16), 256, 0, stream>>>(W1, W1T, 1024, 1024);
  transpose_cvt<<<dim3(32, 8), 256, 0, stream>>>(W2, W2T, 512, 2048);
  prep_small<<<1, 512, 0, stream>>>(lf2, preidx, c2b);

  cvt_full<<<MPAD / 4, 256, 0, stream>>>(inputs, lf1, preidx, Xbf);
  // GEMM1: M=65792 (257 tiles), N=1024 (4 tiles) -> nwg=1028, q=128, r=4
  gemm8p<1024, 4><<<1028, 512, 0, stream>>>(Xbf, W1T, Z1, 128, 4);
  a2_full<<<MPAD / 4, 256, 0, stream>>>(Z1, b1, c2b, A2);
  // GEMM2: M=65792 (257 tiles), N=2048 (8 tiles) -> nwg=2056, q=257, r=0
  gemm8p<512, 8><<<2056, 512, 0, stream>>>(A2, W2T, Z2, 257, 0);
  epilogue_full<<<BSEQ * LSEQ, 256, 0, stream>>>(Z2, Xbf, b2, lnw, out);
}

// Round 5
// 470.940 us; speedup vs baseline: 2.0214x; 1.1610x over previous
//
#include <hip/hip_runtime.h>
#include <hip/hip_bf16.h>

// LocalizedFiltering: two shifted 2-tap causal convs + residual + RMSNorm.
// Fused form: the 2-tap shift is absorbed into K of each GEMM:
//   A2[r+1] = Xbf[r*1024 .. +2048] @ [W1lo;W1hi] + b1        (K=2048, N=512)
//   out2[u] = A2f[r*512 .. +1024] @ [W2lo;W2hi], r=u+(u>>13) (K=1024, N=1024)
// GEMM schedule: 256x256 tile, BK=64, A 3-deep / B 2-deep LDS (160 KB), one
// counted vmcnt(4)+barrier per K-tile (A staged 2 tiles ahead >= HBM latency).

#define EDIM 1024
#define HDIM 512
#define LSEQ 8192
#define BSEQ 8
#define SEQR 8193                 // L+1
#define MTOT (BSEQ * SEQR)        // 65544 extended rows
#define MPAD 65792                // 257 * 256
#define XROWS 66048               // MPAD + 256 (read/write slack, zeroed)

using v8s = __attribute__((ext_vector_type(8))) short;
using v4f = __attribute__((ext_vector_type(4))) float;

__device__ __forceinline__ unsigned short f2b(float f) {
  union { float f; unsigned u; } v; v.f = f;
  unsigned r = v.u + 0x7fffu + ((v.u >> 16) & 1u);   // RNE
  return (unsigned short)(r >> 16);
}
__device__ __forceinline__ float b2f(unsigned short h) {
  union { unsigned u; float f; } v; v.u = ((unsigned)h) << 16; return v.f;
}
__device__ __forceinline__ void gl_lds16(const void* g, void* l) {
  __builtin_amdgcn_global_load_lds((const __attribute__((address_space(1))) void*)g,
                                   (__attribute__((address_space(3))) void*)l, 16, 0, 0);
}

// -------- prep: dst[n][dst_k0+k] = src[k][src_c0+n] (transpose slice -> bf16) --------
__global__ __launch_bounds__(256) void transpose_cat(const float* __restrict__ src, int src_ld,
                                                     int src_c0, unsigned short* __restrict__ dst,
                                                     int dst_ld, int dst_k0) {
  __shared__ float t[64][65];
  const int n0 = blockIdx.x * 64, k0 = blockIdx.y * 64;
  const int tx = threadIdx.x & 63, ty = threadIdx.x >> 6;
#pragma unroll
  for (int yy = 0; yy < 64; yy += 4)
    t[yy + ty][tx] = src[(size_t)(k0 + yy + ty) * src_ld + src_c0 + n0 + tx];
  __syncthreads();
#pragma unroll
  for (int yy = 0; yy < 64; yy += 4)
    dst[(size_t)(n0 + yy + ty) * dst_ld + dst_k0 + k0 + tx] = f2b(t[tx][yy + ty]);
}

// gather the 8 lf2 cache rows as bf16
__global__ void prep_small(const float* __restrict__ lf2, const int* __restrict__ preidx,
                           unsigned short* __restrict__ c2b) {
  const int tid = threadIdx.x;  // 512
#pragma unroll
  for (int b = 0; b < BSEQ; ++b)
    c2b[b * HDIM + tid] = f2b(lf2[(size_t)preidx[b] * HDIM + tid]);
}

// -------- cvt: bf16 extended-A (cache row + shifted tokens, zero pad to XROWS) --------
__global__ __launch_bounds__(256) void cvt_full(const float* __restrict__ inputs,
                                                const float* __restrict__ lf1,
                                                const int* __restrict__ preidx,
                                                unsigned short* __restrict__ Xbf) {
  const int r = blockIdx.x * 4 + (threadIdx.x >> 6);   // 0..XROWS-1
  const int lane = threadIdx.x & 63;
  unsigned short* dst = Xbf + (size_t)r * EDIM;
  if (r >= MTOT) {
#pragma unroll
    for (int c = lane * 4; c < EDIM; c += 256)
      *(ushort4*)&dst[c] = (ushort4){0, 0, 0, 0};
    return;
  }
  const int b = r / SEQR, rr = r % SEQR;
  const float* src = (rr == 0) ? (lf1 + (size_t)preidx[b] * EDIM)
                               : (inputs + (size_t)(b * LSEQ + rr - 1) * EDIM);
#pragma unroll
  for (int c = lane * 4; c < EDIM; c += 256) {
    const float4 v = *(const float4*)(src + c);
    *(ushort4*)&dst[c] = (ushort4){f2b(v.x), f2b(v.y), f2b(v.z), f2b(v.w)};
  }
}

// -------- overwrite the 8 cache rows of A2 with lf2 rows --------
__global__ void fixup_a2(const unsigned short* __restrict__ c2b,
                         unsigned short* __restrict__ A2) {
  const int tid = threadIdx.x;  // 512
#pragma unroll
  for (int b = 0; b < BSEQ; ++b)
    A2[(size_t)(b * SEQR) * HDIM + tid] = c2b[b * HDIM + tid];
}

// ======= 256x256 GEMM, BK=64, 8 waves (2m x 4n), A 3-deep / B 2-deep, 1 wait/tile =======
// C[M][N] = A'[M][K] @ B[N][K]^T. A' rows overlap in memory: row u starts at
// A + umap(u)*LDA (LDA may be < K). AMAP: umap(u)=u+(u>>13); SHIFTC: C row = u+1, +bias.
#define PHASE(p, boA_)                                                                 \
  {                                                                                    \
    v8s af[2][2];                                                                      \
    _Pragma("unroll") for (int m2 = 0; m2 < 2; ++m2)                                   \
    _Pragma("unroll") for (int kx = 0; kx < 2; ++kx)                                   \
      af[m2][kx] = *(const v8s*)&lds[(boA_) + ((2 * (p) + m2) * 32 + wm * 16 + lr) * 64 + \
                                     (((kx * 4 + lk) ^ ra7) << 3)];                    \
    __builtin_amdgcn_s_setprio(1);                                                     \
    _Pragma("unroll") for (int m2 = 0; m2 < 2; ++m2)                                   \
    _Pragma("unroll") for (int nc = 0; nc < 4; ++nc)                                   \
    _Pragma("unroll") for (int kx = 0; kx < 2; ++kx)                                   \
      acc[2 * (p) + m2][nc] = __builtin_amdgcn_mfma_f32_16x16x32_bf16(                 \
          af[m2][kx], bf[nc][kx], acc[2 * (p) + m2][nc], 0, 0, 0);                     \
    __builtin_amdgcn_s_setprio(0);                                                     \
  }

#define LOAD_BFR(boB_)                                                                 \
  _Pragma("unroll") for (int nc = 0; nc < 4; ++nc)                                     \
  _Pragma("unroll") for (int kx = 0; kx < 2; ++kx)                                     \
    bf[nc][kx] = *(const v8s*)&lds[(boB_) + (nc * 64 + wn * 16 + lr) * 64 +            \
                                   (((kx * 4 + lk) ^ ra7) << 3)];

template <int K, int LDA, int NT, bool AMAP, bool SHIFTC>
__global__ __launch_bounds__(512, 2) void gemm3b(const unsigned short* __restrict__ A,
                                                 const unsigned short* __restrict__ B,
                                                 unsigned short* __restrict__ C,
                                                 const float* __restrict__ bias,
                                                 int q, int r) {
  __shared__ __align__(16) unsigned short lds[81920];  // A:3x16384 @0, B:2x16384 @49152 (160 KB)
  constexpr int NTILES = K / 64;
  constexpr int N = NT * 256;
  const int h = blockIdx.x;
  const int xcd = h & 7, idx = h >> 3;
  const int tsw = (xcd < r ? xcd * (q + 1) : r * (q + 1) + (xcd - r) * q) + idx;
  const int mt = tsw / NT, nt = tsw % NT;   // n-fast: neighbors share A m-panel
  const size_t m0 = (size_t)mt * 256, n0 = (size_t)nt * 256;
  const int tid = threadIdx.x;
  const int w = tid >> 6, lane = tid & 63;
  const int wm = w >> 2, wn = w & 3;
  const int lr = lane & 15, lk = lane >> 4;
  const int ra7 = lr & 7;
  const int srow = tid >> 3, slot = tid & 7;
  const int gslot = slot ^ (srow & 7);            // pre-swizzled global 16B-slot
  const int dA = srow * 64 + slot * 8;            // linear LDS dest = wavebase + lane*16B
  const unsigned short* bSrc = B + (size_t)(n0 + srow) * K + gslot * 8;

  auto stageA = [&](int dst, int hh, int tt) {
#pragma unroll
    for (int hf = 0; hf < 2; ++hf) {
      int u = (int)m0 + hh * 128 + hf * 64 + srow;
      if constexpr (AMAP) u += (u >> 13);
      gl_lds16(A + (size_t)u * LDA + tt * 64 + gslot * 8,
               &lds[dst + hh * 8192 + hf * 4096 + dA]);
    }
  };
  auto stageB = [&](int dst, int hh, int tt) {
    const unsigned short* s = bSrc + (size_t)hh * 128 * K + (size_t)tt * 64;
    unsigned short* d = &lds[dst + hh * 8192 + dA];
    gl_lds16(s, d);
    gl_lds16(s + (size_t)64 * K, d + 4096);
  };

  v4f acc[8][4];
#pragma unroll
  for (int i = 0; i < 8; ++i)
#pragma unroll
    for (int j = 0; j < 4; ++j) acc[i][j] = (v4f){0.f, 0.f, 0.f, 0.f};

  // prologue: B(0) -> buf0B, A(0) -> buf0A, A(1) -> buf1A; leave A(1) in flight
  stageB(49152, 0, 0); stageB(49152, 1, 0);
  stageA(0, 0, 0);     stageA(0, 1, 0);
  stageA(16384, 0, 1); stageA(16384, 1, 1);
  asm volatile("s_waitcnt vmcnt(4)" ::: "memory");
  __builtin_amdgcn_s_barrier();

  int boA = 0, soA = 32768;        // read / stage A buffer offsets (elements)
  int boB = 49152, sB = 65536;     // read / stage B buffer offsets
#pragma unroll 1
  for (int t0 = 0; t0 < NTILES - 2; ++t0) {
    v8s bf[4][2];
    stageB(sB, 0, t0 + 1);         // B one tile ahead (L2-resident weights)
    LOAD_BFR(boB)
    PHASE(0, boA)
    stageB(sB, 1, t0 + 1);
    PHASE(1, boA)
    stageA(soA, 0, t0 + 2);        // A two tiles ahead (HBM latency cover)
    PHASE(2, boA)
    stageA(soA, 1, t0 + 2);
    PHASE(3, boA)
    // drain B(t0+1) and A(t0+1); leave A(t0+2)'s 4 loads in flight
    asm volatile("s_waitcnt vmcnt(4)" ::: "memory");
    __builtin_amdgcn_s_barrier();
    const int nboA = (boA == 32768) ? 0 : boA + 16384;
    soA = boA; boA = nboA;
    const int tmp = boB; boB = sB; sB = tmp;
  }
  { // tile NTILES-2: stage last B only; full drain at end
    v8s bf[4][2];
    stageB(sB, 0, NTILES - 1);
    LOAD_BFR(boB)
    PHASE(0, boA)
    stageB(sB, 1, NTILES - 1);
    PHASE(1, boA)
    PHASE(2, boA)
    PHASE(3, boA)
    asm volatile("s_waitcnt vmcnt(0)" ::: "memory");
    __builtin_amdgcn_s_barrier();
    boA = (boA == 32768) ? 0 : boA + 16384;
    const int tmp = boB; boB = sB; sB = tmp;
  }
  { // tile NTILES-1: everything resident
    v8s bf[4][2];
    LOAD_BFR(boB)
    PHASE(0, boA) PHASE(1, boA) PHASE(2, boA) PHASE(3, boA)
  }

#pragma unroll
  for (int mr = 0; mr < 8; ++mr)
#pragma unroll
    for (int nc = 0; nc < 4; ++nc) {
      const size_t col = n0 + nc * 64 + wn * 16 + lr;
      float bv = 0.f;
      if constexpr (SHIFTC) bv = bias[col];
#pragma unroll
      for (int g = 0; g < 4; ++g) {
        const size_t row = m0 + mr * 32 + wm * 16 + lk * 4 + g + (SHIFTC ? 1 : 0);
        C[row * N + col] = f2b(acc[mr][nc][g] + bv);
      }
    }
}

// ---------- epilogue: + b2 + residual(bf16 Xbf) + RMSNorm, one block per token ----------
__global__ __launch_bounds__(256) void epilogue_full(
    const unsigned short* __restrict__ Zo, const unsigned short* __restrict__ Xbf,
    const float* __restrict__ b2, const float* __restrict__ lnw,
    float* __restrict__ out) {
  const int u = blockIdx.x;                       // token id 0..65535
  const size_t rx = (size_t)u + (u >> 13) + 1;    // token's ext row in Xbf
  const int tid = threadIdx.x;
  const int j0 = tid * 4;

  const ushort4 z = *(const ushort4*)&Zo[(size_t)u * EDIM + j0];
  const ushort4 xb = *(const ushort4*)&Xbf[rx * EDIM + j0];   // = bf16(inputs[token])
  const float4 bb = *(const float4*)&b2[j0];
  const float4 lw = *(const float4*)&lnw[j0];

  const float x0 = b2f(z.x) + bb.x + b2f(xb.x);
  const float x1 = b2f(z.y) + bb.y + b2f(xb.y);
  const float x2 = b2f(z.z) + bb.z + b2f(xb.z);
  const float x3 = b2f(z.w) + bb.w + b2f(xb.w);

  float ss = x0 * x0 + x1 * x1 + x2 * x2 + x3 * x3;
#pragma unroll
  for (int o = 32; o > 0; o >>= 1) ss += __shfl_xor(ss, o, 64);
  __shared__ float sp[4];
  if ((tid & 63) == 0) sp[tid >> 6] = ss;
  __syncthreads();
  const float tot = sp[0] + sp[1] + sp[2] + sp[3];
  const float scale = rsqrtf(tot * (1.0f / EDIM) + 1e-6f);

  float4 o4;
  o4.x = x0 * scale * lw.x; o4.y = x1 * scale * lw.y;
  o4.z = x2 * scale * lw.z; o4.w = x3 * scale * lw.w;
  *(float4*)&out[(size_t)u * EDIM + j0] = o4;
}

// -------------------------------- launch --------------------------------
extern "C" void kernel_launch(void* const* d_in, const int* in_sizes, int n_in,
                              void* d_out, int out_size, void* d_ws, size_t ws_size,
                              hipStream_t stream) {
  const float* inputs = (const float*)d_in[0];
  const float* W1 = (const float*)d_in[1];
  const float* W2 = (const float*)d_in[2];
  const float* b1 = (const float*)d_in[3];
  const float* b2 = (const float*)d_in[4];
  const float* lnw = (const float*)d_in[5];
  const float* lf1 = (const float*)d_in[6];
  const float* lf2 = (const float*)d_in[7];
  const int* preidx = (const int*)d_in[8];
  float* out = (float*)d_out;

  char* ws = (char*)d_ws;
  unsigned short* Xbf = (unsigned short*)(ws);                 // XROWS x 1024 = 135,266,304 B
  unsigned short* A2  = (unsigned short*)(ws + 135266304ULL);  // XROWS x  512 =  67,633,152 B
  unsigned short* Zo  = (unsigned short*)(ws + 202899456ULL);  // 65536 x 1024 = 134,217,728 B
  unsigned short* W1c = (unsigned short*)(ws + 337117184ULL);  //  512 x 2048 bf16
  unsigned short* W2c = (unsigned short*)(ws + 339214336ULL);  // 1024 x 1024 bf16
  unsigned short* c2b = (unsigned short*)(ws + 341311488ULL);  // 8 x 512
  // total ws use: ~341 MB

  // W1c[n][k] = k<1024 ? W1[k][n] : W1[k-1024][512+n]   (512 x 2048)
  transpose_cat<<<dim3(8, 16), 256, 0, stream>>>(W1, 1024, 0, W1c, 2048, 0);
  transpose_cat<<<dim3(8, 16), 256, 0, stream>>>(W1, 1024, 512, W1c, 2048, 1024);
  // W2c[n][k] = k<512 ? W2[k][n] : W2[k-512][1024+n]    (1024 x 1024)
  transpose_cat<<<dim3(16, 8), 256, 0, stream>>>(W2, 2048, 0, W2c, 1024, 0);
  transpose_cat<<<dim3(16, 8), 256, 0, stream>>>(W2, 2048, 1024, W2c, 1024, 512);
  prep_small<<<1, 512, 0, stream>>>(lf2, preidx, c2b);

  cvt_full<<<XROWS / 4, 256, 0, stream>>>(inputs, lf1, preidx, Xbf);
  // GEMM1: M=65792 (257 m-tiles) x N=512 (2 n-tiles) -> 514 blocks; q=64, r=2
  gemm3b<2048, 1024, 2, false, true><<<514, 512, 0, stream>>>(Xbf, W1c, A2, b1, 64, 2);
  fixup_a2<<<1, 512, 0, stream>>>(c2b, A2);
  // GEMM2: M=65536 (256 m-tiles) x N=1024 (4 n-tiles) -> 1024 blocks; q=128, r=0
  gemm3b<1024, 512, 4, true, false><<<1024, 512, 0, stream>>>(A2, W2c, Zo, nullptr, 128, 0);
  epilogue_full<<<BSEQ * LSEQ, 256, 0, stream>>>(Zo, Xbf, b2, lnw, out);
}